// Round 10
// baseline (256.348 us; speedup 1.0000x reference)
//
#include <hip/hip_runtime.h>
#include <hip/hip_bf16.h>
#include <stdint.h>

typedef __bf16 bf16;
typedef bf16 bf16x4 __attribute__((ext_vector_type(4)));
typedef bf16 bf16x8 __attribute__((ext_vector_type(8)));
typedef float f32x4 __attribute__((ext_vector_type(4)));

#define LOGSQRT2PI 0.9189385332046727f
#define SB0() __builtin_amdgcn_sched_barrier(0)

__device__ __forceinline__ void gload_lds16(const void* g, void* l) {
    __builtin_amdgcn_global_load_lds((__attribute__((address_space(1))) void*)g,
                                     (__attribute__((address_space(3))) void*)l,
                                     16, 0, 0);
}

// ---- merged weight prep (proven r6): W = mu+(1e-6+softplus(p))*eps ;
// ---- Wt[n][k] bf16 ; lqw/lpw atomics ----
__device__ __forceinline__ void prep_body(const float* __restrict__ mu,
        const float* __restrict__ p, const float* __restrict__ eps,
        bf16* __restrict__ Wt, int N, int Npad, float* __restrict__ osc,
        int vb, int nblocks) {
    int total = 512 * Npad;
    float lqw = 0.f, lpw = 0.f;
    for (int idx = vb * 256 + threadIdx.x; idx < total; idx += nblocks * 256) {
        int k = idx / Npad, n = idx - k * Npad;
        float w = 0.f;
        if (n < N) {
            int src = k * N + n;
            float m = mu[src], e = eps[src];
            float sd = 1e-6f + log1pf(expf(p[src]));
            w = m + sd * e;
            float z = (w - m) / sd;
            lqw += -LOGSQRT2PI - logf(sd) - 0.5f * z * z;
            lpw += -LOGSQRT2PI - 0.5f * w * w;
        }
        Wt[n * 512 + k] = (bf16)w;
    }
    #pragma unroll
    for (int off = 32; off; off >>= 1) {
        lqw += __shfl_down(lqw, off);
        lpw += __shfl_down(lpw, off);
    }
    if ((threadIdx.x & 63) == 0) {
        atomicAdd(&osc[0], lqw);
        atomicAdd(&osc[1], lpw);
    }
}

__global__ void k_prep_all(const float* __restrict__ mu1, const float* __restrict__ p1,
                           const float* __restrict__ e1,
                           const float* __restrict__ mu2, const float* __restrict__ p2,
                           const float* __restrict__ e2,
                           const float* __restrict__ mu3, const float* __restrict__ p3,
                           const float* __restrict__ e3,
                           bf16* __restrict__ Wt1, bf16* __restrict__ Wt2,
                           bf16* __restrict__ Wt3, float* __restrict__ osc) {
    int b = blockIdx.x;
    if (b < 256)      prep_body(mu1, p1, e1, Wt1, 512, 512, osc, b, 256);
    else if (b < 512) prep_body(mu2, p2, e2, Wt2, 512, 512, osc, b - 256, 256);
    else              prep_body(mu3, p3, e3, Wt3, 10,  16,  osc, b - 512, 16);
}

// ---- x fp32 -> bf16 (row-major) ----
__global__ void k_cvt(const float4* __restrict__ in, bf16x4* __restrict__ out, int n4) {
    int stride = gridDim.x * blockDim.x;
    for (int i = blockIdx.x * blockDim.x + threadIdx.x; i < n4; i += stride) {
        float4 v = in[i];
        bf16x4 o;
        o[0] = (bf16)v.x; o[1] = (bf16)v.y; o[2] = (bf16)v.z; o[3] = (bf16)v.w;
        out[i] = o;
    }
}

// ============================================================================
// B-stationary M-STREAMING GEMM (barrier-free after one B-fill).
//   Block = 8 waves (512 thr); B-slice 64 cols x 512 K resident in LDS (64 KB,
//   64 fragment chunks c = kt*4+jg).  Each wave owns 32 rows per M-tile and
//   streams 8 M-tiles x 16 K-steps = 128 uninterrupted iterations: the
//   pipeline NEVER drains between tiles (m97's amortization regime, vs the
//   8-16-iter fill/drain that capped rounds 1-9 at ~425 TF).
//   Wave-exclusive staging: wave w gload_lds's its OWN chunks (2w, 2w+1) of
//   each A-buf -> produced and consumed by the same wave -> NO barriers, no
//   cross-wave convoy; per-wave counted vmcnt(2) gates, depth-2 prefetch,
//   3 A-bufs (48 KB).  LDS total 144 KB -> 1 block/CU, 8 self-paced waves.
//   Sources are 64B-line coalesced (16 rows x 64B per STG instruction).
//   Grid 256 = 8 slices x 32 M-windows; bid = s*32+m -> all 8 slices of a
//   window land on XCD m%8 (A fetched from HBM once, 7x L2 hits).
//   Epilogue per M-tile (in-stream, wave-private scrT 4 KB, r8-proven
//   swizzle phys = row*64 + (((col>>3)^(row&7))<<3) + (col&7)):
//     G1: h1 rows stored row-major via b128 (coalesced).
//     G2: fused layer-3 partial vs W3 slice + atomicAdd into y (r4/r6-proven).
// ============================================================================
template<bool FUSE3>
__global__ __launch_bounds__(512, 1)
void k_gemm(const bf16* __restrict__ A, const bf16* __restrict__ Bt,
            bf16* __restrict__ C, const bf16* __restrict__ W3t,
            float* __restrict__ Y) {
    __shared__ __align__(16) bf16 L[73728];   // 48KB A(3buf) + 64KB B + 32KB scrT
    const int tid = threadIdx.x;
    const int l = tid & 63, w = tid >> 6;
    const int r = l & 15, kq = l >> 4;
    const int l8 = l * 8;
    const int sl = blockIdx.x >> 5;          // slice 0..7
    const int m  = blockIdx.x & 31;          // M-window 0..31 (XCD = m%8)
    const int cb = sl * 64;
    const long mb = (long)m * 2048;
    bf16* scr = &L[57344 + w * 2048];

    // ---- one-time B fill: 64 chunks, wave w covers c = i*8+w ----
    #pragma unroll
    for (int i = 0; i < 8; i++) {
        int c = i * 8 + w;
        int kt = c >> 2, jg = c & 3;
        gload_lds16(Bt + (long)(cb + jg * 16 + r) * 512 + kt * 32 + kq * 8,
                    &L[24576 + c * 512 + l8]);
    }
    bf16x8 b3[2];
    if (FUSE3) {
        b3[0] = *(const bf16x8*)(W3t + r * 512 + cb + kq * 8);
        b3[1] = *(const bf16x8*)(W3t + r * 512 + cb + 32 + kq * 8);
    }

    // wave w stages its own chunks (2w, 2w+1): rows w*32 + {0..31}
    #define STG(IT, BUF) do {                                                  \
        _Pragma("unroll")                                                      \
        for (int s2 = 0; s2 < 2; s2++)                                         \
            gload_lds16(A + (mb + (long)((IT) >> 4) * 256 + w * 32 + s2 * 16 + r) * 512 \
                          + ((IT) & 15) * 32 + kq * 8,                         \
                        &L[(BUF) * 8192 + (w * 2 + s2) * 512 + l8]);           \
    } while (0)

    STG(0, 0);
    STG(1, 1);
    asm volatile("s_waitcnt vmcnt(2)" ::: "memory");  // B + b3 + STG(0) landed
    __builtin_amdgcn_s_barrier();                     // the only barrier

    f32x4 acc[2][4];
    #pragma unroll
    for (int i = 0; i < 2; i++)
        #pragma unroll
        for (int j = 0; j < 4; j++) acc[i][j] = (f32x4){0.f, 0.f, 0.f, 0.f};

    for (int mt = 0; mt < 8; mt++) {
        #pragma unroll
        for (int kt = 0; kt < 16; kt++) {
            const int it = mt * 16 + kt;
            if (it < 126) STG(it + 2, (it + 2) % 3);
            const int buf = it % 3;
            bf16x8 a0 = *(const bf16x8*)&L[buf * 8192 + (w * 2) * 512 + l8];
            bf16x8 a1 = *(const bf16x8*)&L[buf * 8192 + (w * 2 + 1) * 512 + l8];
            #pragma unroll
            for (int j = 0; j < 4; j++) {
                bf16x8 bf_ = *(const bf16x8*)&L[24576 + (kt * 4 + j) * 512 + l8];
                acc[0][j] = __builtin_amdgcn_mfma_f32_16x16x32_bf16(a0, bf_, acc[0][j], 0, 0, 0);
                acc[1][j] = __builtin_amdgcn_mfma_f32_16x16x32_bf16(a1, bf_, acc[1][j], 0, 0, 0);
            }
            if (it < 126)       { asm volatile("s_waitcnt vmcnt(2)" ::: "memory"); }
            else if (it == 126) { asm volatile("s_waitcnt vmcnt(0)" ::: "memory"); }
        }

        // ---- in-stream epilogue for tile mt (wave-private) ----
        const long m0 = mb + mt * 256 + w * 32;
        #pragma unroll
        for (int i = 0; i < 2; i++)
            #pragma unroll
            for (int j = 0; j < 4; j++)
                #pragma unroll
                for (int q = 0; q < 4; q++) {
                    int row = i * 16 + kq * 4 + q;
                    int col = j * 16 + r;
                    float v = fmaxf(acc[i][j][q], 0.f);
                    scr[row * 64 + (((col >> 3) ^ (row & 7)) << 3) + (col & 7)] = (bf16)v;
                }
        asm volatile("s_waitcnt lgkmcnt(0)" ::: "memory");
        SB0();
        if (!FUSE3) {
            // h1 row-major store: 8 rows x 64-col segment per b128 instr
            #pragma unroll
            for (int rr = 0; rr < 4; rr++) {
                int row = rr * 8 + (l >> 3);
                bf16x8 v = *(const bf16x8*)&scr[row * 64 + (((l & 7) ^ (row & 7)) << 3)];
                *(bf16x8*)(C + (m0 + row) * 512 + cb + (l & 7) * 8) = v;
            }
        } else {
            f32x4 ya = (f32x4){0.f, 0.f, 0.f, 0.f};
            f32x4 yb = (f32x4){0.f, 0.f, 0.f, 0.f};
            #pragma unroll
            for (int ktl = 0; ktl < 2; ktl++) {
                bf16x8 aA = *(const bf16x8*)&scr[r * 64 + (((ktl * 4 + kq) ^ (r & 7)) << 3)];
                bf16x8 aB = *(const bf16x8*)&scr[(16 + r) * 64 + (((ktl * 4 + kq) ^ (r & 7)) << 3)];
                ya = __builtin_amdgcn_mfma_f32_16x16x32_bf16(aA, b3[ktl], ya, 0, 0, 0);
                yb = __builtin_amdgcn_mfma_f32_16x16x32_bf16(aB, b3[ktl], yb, 0, 0, 0);
            }
            if (r < 10) {
                #pragma unroll
                for (int q = 0; q < 4; q++) {
                    atomicAdd(Y + (m0 + kq * 4 + q) * 10 + r, ya[q]);
                    atomicAdd(Y + (m0 + 16 + kq * 4 + q) * 10 + r, yb[q]);
                }
            }
        }
        asm volatile("s_waitcnt lgkmcnt(0)" ::: "memory");  // scr reads before next tile
        SB0();
        #pragma unroll
        for (int i = 0; i < 2; i++)
            #pragma unroll
            for (int j = 0; j < 4; j++) acc[i][j] = (f32x4){0.f, 0.f, 0.f, 0.f};
    }
    #undef STG
}

extern "C" void kernel_launch(void* const* d_in, const int* in_sizes, int n_in,
                              void* d_out, int out_size, void* d_ws, size_t ws_size,
                              hipStream_t stream) {
    const float* x   = (const float*)d_in[0];
    const float* mu1 = (const float*)d_in[1];
    const float* p1  = (const float*)d_in[2];
    const float* e1  = (const float*)d_in[3];
    const float* mu2 = (const float*)d_in[4];
    const float* p2  = (const float*)d_in[5];
    const float* e2  = (const float*)d_in[6];
    const float* mu3 = (const float*)d_in[7];
    const float* p3  = (const float*)d_in[8];
    const float* e3  = (const float*)d_in[9];
    float* out = (float*)d_out;

    const int B = 65536, D = 512, DO = 10;

    char* ws = (char*)d_ws;
    bf16* Wt1 = (bf16*)(ws);
    bf16* Wt2 = (bf16*)(ws + 524288);
    bf16* Wt3 = (bf16*)(ws + 1048576);
    bf16* xb  = (bf16*)(ws + 1114112);
    bf16* h1  = (bf16*)(ws + 1114112 + 67108864);

    float* osc = out + (long)B * DO;

    hipMemsetAsync(out, 0, (size_t)out_size * sizeof(float), stream);
    hipLaunchKernelGGL(k_prep_all, dim3(528), dim3(256), 0, stream,
                       mu1, p1, e1, mu2, p2, e2, mu3, p3, e3, Wt1, Wt2, Wt3, osc);
    hipLaunchKernelGGL(k_cvt, dim3(2048), dim3(256), 0, stream,
                       (const float4*)x, (bf16x4*)xb, B * D / 4);
    hipLaunchKernelGGL((k_gemm<false>), dim3(256), dim3(512), 0, stream,
                       xb, Wt1, h1, (const bf16*)nullptr, (float*)nullptr);
    hipLaunchKernelGGL((k_gemm<true>), dim3(256), dim3(512), 0, stream,
                       h1, Wt2, (bf16*)nullptr, Wt3, out);
}

// Round 11
// 217.432 us; speedup vs baseline: 1.1790x; 1.1790x over previous
//
#include <hip/hip_runtime.h>
#include <hip/hip_bf16.h>
#include <stdint.h>

typedef __bf16 bf16;
typedef bf16 bf16x4 __attribute__((ext_vector_type(4)));
typedef bf16 bf16x8 __attribute__((ext_vector_type(8)));
typedef float f32x4 __attribute__((ext_vector_type(4)));

#define LOGSQRT2PI 0.9189385332046727f
#define SB0() __builtin_amdgcn_sched_barrier(0)

__device__ __forceinline__ void gload_lds16(const void* g, void* l) {
    __builtin_amdgcn_global_load_lds((__attribute__((address_space(1))) void*)g,
                                     (__attribute__((address_space(3))) void*)l,
                                     16, 0, 0);
}

// ---- merged weight prep (proven r6) ----
__device__ __forceinline__ void prep_body(const float* __restrict__ mu,
        const float* __restrict__ p, const float* __restrict__ eps,
        bf16* __restrict__ Wt, int N, int Npad, float* __restrict__ osc,
        int vb, int nblocks) {
    int total = 512 * Npad;
    float lqw = 0.f, lpw = 0.f;
    for (int idx = vb * 256 + threadIdx.x; idx < total; idx += nblocks * 256) {
        int k = idx / Npad, n = idx - k * Npad;
        float w = 0.f;
        if (n < N) {
            int src = k * N + n;
            float m = mu[src], e = eps[src];
            float sd = 1e-6f + log1pf(expf(p[src]));
            w = m + sd * e;
            float z = (w - m) / sd;
            lqw += -LOGSQRT2PI - logf(sd) - 0.5f * z * z;
            lpw += -LOGSQRT2PI - 0.5f * w * w;
        }
        Wt[n * 512 + k] = (bf16)w;
    }
    #pragma unroll
    for (int off = 32; off; off >>= 1) {
        lqw += __shfl_down(lqw, off);
        lpw += __shfl_down(lpw, off);
    }
    if ((threadIdx.x & 63) == 0) {
        atomicAdd(&osc[0], lqw);
        atomicAdd(&osc[1], lpw);
    }
}

__global__ void k_prep_all(const float* __restrict__ mu1, const float* __restrict__ p1,
                           const float* __restrict__ e1,
                           const float* __restrict__ mu2, const float* __restrict__ p2,
                           const float* __restrict__ e2,
                           const float* __restrict__ mu3, const float* __restrict__ p3,
                           const float* __restrict__ e3,
                           bf16* __restrict__ Wt1, bf16* __restrict__ Wt2,
                           bf16* __restrict__ Wt3, float* __restrict__ osc) {
    int b = blockIdx.x;
    if (b < 256)      prep_body(mu1, p1, e1, Wt1, 512, 512, osc, b, 256);
    else if (b < 512) prep_body(mu2, p2, e2, Wt2, 512, 512, osc, b - 256, 256);
    else              prep_body(mu3, p3, e3, Wt3, 10,  16,  osc, b - 512, 16);
}

// ---- x fp32 -> bf16 ----
__global__ void k_cvt(const float4* __restrict__ in, bf16x4* __restrict__ out, int n4) {
    int stride = gridDim.x * blockDim.x;
    for (int i = blockIdx.x * blockDim.x + threadIdx.x; i < n4; i += stride) {
        float4 v = in[i];
        bf16x4 o;
        o[0] = (bf16)v.x; o[1] = (bf16)v.y; o[2] = (bf16)v.z; o[3] = (bf16)v.w;
        out[i] = o;
    }
}

// ============================================================================
// LONG-STREAM lockstep GEMM: 128x256 tile, BK=32, 8 waves (2M x 4N), 4 LDS
// buffers (depth-3 prefetch, vmcnt(6) = 3-iter latency budget), 64-iteration
// continuous K-stream (4 bm-tiles per block, pipeline never drains between
// tiles).  Grid 256 = 1 block/CU; bn = bid>>7 so A-sharing pairs (g, g+128)
// land on the same XCD's L2.
// LDS (128 KB): 4 bufs x 12288 elems (A 8 chunks + B 16 chunks, 1KB fragment
// chunks, conflict-free) + 16384-elem bounce (128x128 half-tile, 16B-chunk
// XOR swizzle phys_chunk = cc ^ (row&7), r8-proven).
// vmcnt accounting (in-order retirement, m135): 3 loads/iter; stores issued
// in epilogue count in program order -> post-epilogue gates vmcnt(14) [g1,
// 8 stores] / vmcnt(10) [g2, 4 atomics]; steady vmcnt(6); tail 3->0.
// ============================================================================
template<bool FUSE3>
__global__ __launch_bounds__(512, 1)
void k_gemm(const bf16* __restrict__ A, const bf16* __restrict__ Bt,
            bf16* __restrict__ C, const bf16* __restrict__ W3t,
            float* __restrict__ Y) {
    __shared__ __align__(16) bf16 L[65536];   // 128 KB
    const int tid = threadIdx.x;
    const int l = tid & 63, w = tid >> 6;
    const int r = l & 15, kq = l >> 4;
    const int l8 = l * 8;
    const int wm = w >> 2, wn = w & 3;
    const int bn  = blockIdx.x >> 7;          // 0/1
    const int grp = blockIdx.x & 127;
    bf16* BNC = &L[49152];                    // bounce half-tile [128][128]

    // staging: per iter IT (tile IT>>4, k-step IT&15), 3 gloads/thread:
    //   A chunk rg=w (rows bm + w*16 + r), B chunks rg=2w,2w+1
    #define STG(IT, BUF) do {                                                  \
        const long bmI = (long)(grp * 4 + ((IT) >> 4)) * 128;                  \
        const int kk = ((IT) & 15) * 32;                                       \
        gload_lds16(A + (bmI + w * 16 + r) * 512 + kk + kq * 8,                \
                    &L[(BUF) * 12288 + w * 512 + l8]);                         \
        gload_lds16(Bt + ((long)bn * 256 + (2 * w) * 16 + r) * 512 + kk + kq * 8, \
                    &L[(BUF) * 12288 + 4096 + (2 * w) * 512 + l8]);            \
        gload_lds16(Bt + ((long)bn * 256 + (2 * w + 1) * 16 + r) * 512 + kk + kq * 8, \
                    &L[(BUF) * 12288 + 4096 + (2 * w + 1) * 512 + l8]);        \
    } while (0)

    bf16x8 b3[8];
    if (FUSE3) {
        #pragma unroll
        for (int ks = 0; ks < 8; ks++)
            b3[ks] = *(const bf16x8*)(W3t + r * 512 + bn * 256 + ks * 32 + kq * 8);
    }

    f32x4 acc[4][4];
    #pragma unroll
    for (int i = 0; i < 4; i++)
        #pragma unroll
        for (int j = 0; j < 4; j++) acc[i][j] = (f32x4){0.f, 0.f, 0.f, 0.f};
    bf16x8 afr[4], bfr[4];

    // prologue: 3 batches in flight
    STG(0, 0); STG(1, 1); STG(2, 2);
    asm volatile("s_waitcnt vmcnt(6)" ::: "memory");   // batch0 done
    __builtin_amdgcn_s_barrier();

    for (int it = 0; it < 64; ++it) {
        const int buf = it & 3;
        if (it < 61) STG(it + 3, (it + 3) & 3);        // distinct from buf mod 4
        #pragma unroll
        for (int i = 0; i < 4; i++)
            afr[i] = *(const bf16x8*)&L[buf * 12288 + (wm * 4 + i) * 512 + l8];
        #pragma unroll
        for (int j = 0; j < 4; j++)
            bfr[j] = *(const bf16x8*)&L[buf * 12288 + 4096 + (wn * 4 + j) * 512 + l8];
        __builtin_amdgcn_s_setprio(1);
        #pragma unroll
        for (int i = 0; i < 4; i++)
            #pragma unroll
            for (int j = 0; j < 4; j++)
                acc[i][j] = __builtin_amdgcn_mfma_f32_16x16x32_bf16(
                    afr[i], bfr[j], acc[i][j], 0, 0, 0);
        __builtin_amdgcn_s_setprio(0);

        // ---- gate (derived; stores count in-order in vmcnt) ----
        const int k15 = it & 15;
        if (it >= 16 && k15 <= 1) {
            if (FUSE3) { asm volatile("s_waitcnt vmcnt(10)" ::: "memory"); }
            else       { asm volatile("s_waitcnt vmcnt(14)" ::: "memory"); }
        } else if (it == 61) { asm volatile("s_waitcnt vmcnt(3)" ::: "memory"); }
        else if (it == 62)   { asm volatile("s_waitcnt vmcnt(0)" ::: "memory"); }
        else if (it != 63)   { asm volatile("s_waitcnt vmcnt(6)" ::: "memory"); }
        __builtin_amdgcn_s_barrier();

        // ---- tile epilogue every 16 iters (pipeline stays in flight) ----
        if (k15 == 15) {
            const long bm = (long)(grp * 4 + (it >> 4)) * 128;
            f32x4 yacc = (f32x4){0.f, 0.f, 0.f, 0.f};
            #pragma unroll
            for (int h = 0; h < 2; h++) {
                // write half h: waves with wn>>1 == h
                if ((wn >> 1) == h) {
                    #pragma unroll
                    for (int i = 0; i < 4; i++)
                        #pragma unroll
                        for (int j = 0; j < 4; j++)
                            #pragma unroll
                            for (int q = 0; q < 4; q++) {
                                int row = wm * 64 + i * 16 + kq * 4 + q;
                                int col = (wn & 1) * 64 + j * 16 + r;
                                float v = fmaxf(acc[i][j][q], 0.f);
                                BNC[row * 128 + (((col >> 3) ^ (row & 7)) << 3) + (col & 7)] = (bf16)v;
                            }
                }
                asm volatile("s_waitcnt lgkmcnt(0)" ::: "memory");
                __builtin_amdgcn_s_barrier();
                if (!FUSE3) {
                    #pragma unroll
                    for (int s = 0; s < 4; s++) {
                        int row = s * 32 + (tid >> 4);
                        int cc = tid & 15;
                        bf16x8 v = *(const bf16x8*)&BNC[row * 128 + ((cc ^ (row & 7)) << 3)];
                        *(bf16x8*)(C + (bm + row) * 512 + bn * 256 + h * 128 + cc * 8) = v;
                    }
                } else {
                    #pragma unroll
                    for (int ks = 0; ks < 4; ks++) {
                        int row = w * 16 + r;
                        int cc = ks * 4 + kq;
                        bf16x8 a3 = *(const bf16x8*)&BNC[row * 128 + ((cc ^ (row & 7)) << 3)];
                        yacc = __builtin_amdgcn_mfma_f32_16x16x32_bf16(a3, b3[h * 4 + ks], yacc, 0, 0, 0);
                    }
                }
                asm volatile("s_waitcnt lgkmcnt(0)" ::: "memory");
                __builtin_amdgcn_s_barrier();
            }
            if (FUSE3 && r < 10) {
                #pragma unroll
                for (int q = 0; q < 4; q++)
                    atomicAdd(Y + (bm + w * 16 + kq * 4 + q) * 10 + r, yacc[q]);
            }
            #pragma unroll
            for (int i = 0; i < 4; i++)
                #pragma unroll
                for (int j = 0; j < 4; j++) acc[i][j] = (f32x4){0.f, 0.f, 0.f, 0.f};
        }
    }
    #undef STG
}

extern "C" void kernel_launch(void* const* d_in, const int* in_sizes, int n_in,
                              void* d_out, int out_size, void* d_ws, size_t ws_size,
                              hipStream_t stream) {
    const float* x   = (const float*)d_in[0];
    const float* mu1 = (const float*)d_in[1];
    const float* p1  = (const float*)d_in[2];
    const float* e1  = (const float*)d_in[3];
    const float* mu2 = (const float*)d_in[4];
    const float* p2  = (const float*)d_in[5];
    const float* e2  = (const float*)d_in[6];
    const float* mu3 = (const float*)d_in[7];
    const float* p3  = (const float*)d_in[8];
    const float* e3  = (const float*)d_in[9];
    float* out = (float*)d_out;

    const int B = 65536, D = 512, DO = 10;

    char* ws = (char*)d_ws;
    bf16* Wt1 = (bf16*)(ws);
    bf16* Wt2 = (bf16*)(ws + 524288);
    bf16* Wt3 = (bf16*)(ws + 1048576);
    bf16* xb  = (bf16*)(ws + 1114112);
    bf16* h1  = (bf16*)(ws + 1114112 + 67108864);

    float* osc = out + (long)B * DO;

    hipMemsetAsync(out, 0, (size_t)out_size * sizeof(float), stream);
    hipLaunchKernelGGL(k_prep_all, dim3(528), dim3(256), 0, stream,
                       mu1, p1, e1, mu2, p2, e2, mu3, p3, e3, Wt1, Wt2, Wt3, osc);
    hipLaunchKernelGGL(k_cvt, dim3(2048), dim3(256), 0, stream,
                       (const float4*)x, (bf16x4*)xb, B * D / 4);
    hipLaunchKernelGGL((k_gemm<false>), dim3(256), dim3(512), 0, stream,
                       xb, Wt1, h1, (const bf16*)nullptr, (float*)nullptr);
    hipLaunchKernelGGL((k_gemm<true>), dim3(256), dim3(512), 0, stream,
                       h1, Wt2, (bf16*)nullptr, Wt3, out);
}

// Round 12
// 194.279 us; speedup vs baseline: 1.3195x; 1.1192x over previous
//
#include <hip/hip_runtime.h>
#include <hip/hip_bf16.h>
#include <stdint.h>

typedef unsigned char u8;
typedef unsigned int u32;
typedef long i64;
typedef i64 i64x2 __attribute__((ext_vector_type(2)));
typedef float f32x4 __attribute__((ext_vector_type(4)));

#define LOGSQRT2PI 0.9189385332046727f

__device__ __forceinline__ void gload_lds16(const void* g, void* l) {
    __builtin_amdgcn_global_load_lds((__attribute__((address_space(1))) void*)g,
                                     (__attribute__((address_space(3))) void*)l,
                                     16, 0, 0);
}

__device__ __forceinline__ u8 to_fp8(float v) {
    return (u8)(__builtin_amdgcn_cvt_pk_fp8_f32(v, 0.f, 0, false) & 0xff);
}

// ---- merged weight prep (r6-proven math): W = mu+(1e-6+softplus(p))*eps ;
// ---- Wt[n][k] fp8 e4m3 ; lqw/lpw fp32-exact atomics ----
__device__ __forceinline__ void prep_body(const float* __restrict__ mu,
        const float* __restrict__ p, const float* __restrict__ eps,
        u8* __restrict__ Wt, int N, int Npad, float* __restrict__ osc,
        int vb, int nblocks) {
    int total = 512 * Npad;
    float lqw = 0.f, lpw = 0.f;
    for (int idx = vb * 256 + threadIdx.x; idx < total; idx += nblocks * 256) {
        int k = idx / Npad, n = idx - k * Npad;
        float w = 0.f;
        if (n < N) {
            int src = k * N + n;
            float m = mu[src], e = eps[src];
            float sd = 1e-6f + log1pf(expf(p[src]));
            w = m + sd * e;
            float z = (w - m) / sd;
            lqw += -LOGSQRT2PI - logf(sd) - 0.5f * z * z;
            lpw += -LOGSQRT2PI - 0.5f * w * w;
        }
        Wt[n * 512 + k] = to_fp8(w);
    }
    #pragma unroll
    for (int off = 32; off; off >>= 1) {
        lqw += __shfl_down(lqw, off);
        lpw += __shfl_down(lpw, off);
    }
    if ((threadIdx.x & 63) == 0) {
        atomicAdd(&osc[0], lqw);
        atomicAdd(&osc[1], lpw);
    }
}

__global__ void k_prep_all(const float* __restrict__ mu1, const float* __restrict__ p1,
                           const float* __restrict__ e1,
                           const float* __restrict__ mu2, const float* __restrict__ p2,
                           const float* __restrict__ e2,
                           const float* __restrict__ mu3, const float* __restrict__ p3,
                           const float* __restrict__ e3,
                           u8* __restrict__ Wt1, u8* __restrict__ Wt2,
                           u8* __restrict__ Wt3, float* __restrict__ osc) {
    int b = blockIdx.x;
    if (b < 256)      prep_body(mu1, p1, e1, Wt1, 512, 512, osc, b, 256);
    else if (b < 512) prep_body(mu2, p2, e2, Wt2, 512, 512, osc, b - 256, 256);
    else              prep_body(mu3, p3, e3, Wt3, 10,  16,  osc, b - 512, 16);
}

// ---- x fp32 -> fp8 (8 floats -> 8 bytes per iter) ----
__global__ void k_cvt8(const float4* __restrict__ in, uint2* __restrict__ out, int n8) {
    int stride = gridDim.x * blockDim.x;
    for (int i = blockIdx.x * blockDim.x + threadIdx.x; i < n8; i += stride) {
        float4 a = in[2 * i], b = in[2 * i + 1];
        u32 lo = __builtin_amdgcn_cvt_pk_fp8_f32(a.x, a.y, 0, false);
        lo = __builtin_amdgcn_cvt_pk_fp8_f32(a.z, a.w, (int)lo, true);
        u32 hi = __builtin_amdgcn_cvt_pk_fp8_f32(b.x, b.y, 0, false);
        hi = __builtin_amdgcn_cvt_pk_fp8_f32(b.z, b.w, (int)hi, true);
        out[i] = make_uint2(lo, hi);
    }
}

// ============================================================================
// fp8 256x256 GEMM, 8 waves (2M x 4N), wave tile 128x64, BK=64, dbuf 64 KB.
// Staging chunk = 16 rows x K=64 = 1024 B = ONE gload_lds16/wave: lane l holds
// row l&15, k-window (l>>4)*16 (16 contiguous global bytes).  One ds_read_b128
// yields TWO fp8-MFMA k-steps (byte halves) under the permuted-k pairing:
// operand pos (kq,j,half) |-> global k = kt*64 + kq*16 + half*8 + j, identical
// for A and B => contraction pairs identical global k.  Per tile: 4 gloads/thr,
// 12 b128/wave, 64 MFMA, vmcnt(0), ONE barrier.  STG(T+1)->nb issued BEFORE
// reads+MFMAs: the ~400cy MFMA phase covers the load latency, so the depth-1
// drain is ~free.  No races: nb is untouched by this tile's readers.
// ============================================================================
#define MFMA8(A, B, C) __builtin_amdgcn_mfma_f32_16x16x32_fp8_fp8(A, B, C, 0, 0, 0)

template<bool FUSE3>
__global__ __launch_bounds__(512, 1)
void k_g8(const u8* __restrict__ A, const u8* __restrict__ Bt,
          u8* __restrict__ C, const u8* __restrict__ W3t,
          float* __restrict__ Y) {
    __shared__ __align__(16) u8 L[65536];   // A: 2x16KB, B: 2x16KB; reused post-loop
    const int tid = threadIdx.x;
    const int l = tid & 63, w = tid >> 6;
    const int r = l & 15, kq = l >> 4;
    const int l16 = l * 16;
    const int wm = w >> 2, wn = w & 3;

    const int bid = blockIdx.x;
    const int logical = (bid & 7) * 64 + (bid >> 3);   // 512 % 8 == 0: bijective
    const long bm = (long)(logical >> 1) * 256;
    const int  bn = (logical & 1) * 256;

    const u8* Asrc = A  + (bm + r) * 512 + kq * 16;
    const u8* Bsrc = Bt + ((long)bn + r) * 512 + kq * 16;

    #define STG(T, BUF) do {                                                   \
        gload_lds16(Asrc + (w) * (16 * 512) + (T) * 64,                        \
                    &L[(BUF) * 16384 + (w) * 1024 + l16]);                     \
        gload_lds16(Asrc + (8 + w) * (16 * 512) + (T) * 64,                    \
                    &L[(BUF) * 16384 + (8 + w) * 1024 + l16]);                 \
        gload_lds16(Bsrc + (w) * (16 * 512) + (T) * 64,                        \
                    &L[32768 + (BUF) * 16384 + (w) * 1024 + l16]);             \
        gload_lds16(Bsrc + (8 + w) * (16 * 512) + (T) * 64,                    \
                    &L[32768 + (BUF) * 16384 + (8 + w) * 1024 + l16]);         \
    } while (0)

    f32x4 acc[8][4];
    #pragma unroll
    for (int i = 0; i < 8; i++)
        #pragma unroll
        for (int j = 0; j < 4; j++) acc[i][j] = (f32x4){0.f, 0.f, 0.f, 0.f};

    STG(0, 0);
    asm volatile("s_waitcnt vmcnt(0)" ::: "memory");
    __builtin_amdgcn_s_barrier();

    for (int T = 0; T < 8; ++T) {
        const int buf = T & 1;
        if (T < 7) STG(T + 1, buf ^ 1);        // latency covered by this tile's MFMAs
        i64x2 afr[8], bfr[4];
        #pragma unroll
        for (int i = 0; i < 8; i++)
            afr[i] = *(const i64x2*)&L[buf * 16384 + (wm * 8 + i) * 1024 + l16];
        #pragma unroll
        for (int j = 0; j < 4; j++)
            bfr[j] = *(const i64x2*)&L[32768 + buf * 16384 + (wn * 4 + j) * 1024 + l16];
        __builtin_amdgcn_s_setprio(1);
        #pragma unroll
        for (int i = 0; i < 8; i++)
            #pragma unroll
            for (int j = 0; j < 4; j++) {
                acc[i][j] = MFMA8(afr[i].x, bfr[j].x, acc[i][j]);
                acc[i][j] = MFMA8(afr[i].y, bfr[j].y, acc[i][j]);
            }
        __builtin_amdgcn_s_setprio(0);
        if (T < 7) { asm volatile("s_waitcnt vmcnt(0)" ::: "memory"); }
        __builtin_amdgcn_s_barrier();
    }

    if (!FUSE3) {
        // h1 tile -> LDS bounce [256][256] fp8 (ReLU; 16B-chunk swizzle
        // phys = (cc ^ (row&15))<<4) -> coalesced 16B global stores
        #pragma unroll
        for (int i = 0; i < 8; i++)
            #pragma unroll
            for (int j = 0; j < 4; j++)
                #pragma unroll
                for (int q = 0; q < 4; q++) {
                    int row = wm * 128 + i * 16 + kq * 4 + q;
                    int cc = wn * 4 + j;
                    L[row * 256 + (((cc ^ (row & 15)) << 4)) + r] =
                        to_fp8(fmaxf(acc[i][j][q], 0.f));
                }
        asm volatile("s_waitcnt lgkmcnt(0)" ::: "memory");
        __builtin_amdgcn_s_barrier();
        #pragma unroll
        for (int s = 0; s < 8; s++) {
            int row = s * 32 + (tid >> 4);
            int cc = tid & 15;
            i64x2 v = *(const i64x2*)&L[row * 256 + ((cc ^ (row & 15)) << 4)];
            *(i64x2*)(C + (bm + row) * 512 + bn + cc * 16) = v;
        }
    } else {
        // fused layer 3: h2 -> wave-private scr (8 chunks, frag order) -> MFMA
        // vs W3 k-slice (bn + wn*64) -> atomicAdd into y
        #pragma unroll
        for (int i = 0; i < 8; i++)
            #pragma unroll
            for (int j = 0; j < 4; j++)
                #pragma unroll
                for (int q = 0; q < 4; q++) {
                    L[w * 8192 + i * 1024 + (kq * 4 + q) * 16 + j * 256 + r] =
                        to_fp8(fmaxf(acc[i][j][q], 0.f));
                }
        i64x2 b3 = *(const i64x2*)(W3t + r * 512 + bn + wn * 64 + kq * 16);
        asm volatile("s_waitcnt lgkmcnt(0)" ::: "memory");
        f32x4 yacc[8];
        #pragma unroll
        for (int rg = 0; rg < 8; rg++) yacc[rg] = (f32x4){0.f, 0.f, 0.f, 0.f};
        #pragma unroll
        for (int rg = 0; rg < 8; rg++) {
            i64x2 a3 = *(const i64x2*)&L[w * 8192 + rg * 1024 + l16];
            yacc[rg] = MFMA8(a3.x, b3.x, yacc[rg]);
            yacc[rg] = MFMA8(a3.y, b3.y, yacc[rg]);
        }
        if (r < 10) {
            #pragma unroll
            for (int rg = 0; rg < 8; rg++)
                #pragma unroll
                for (int q = 0; q < 4; q++) {
                    long row = bm + wm * 128 + rg * 16 + kq * 4 + q;
                    atomicAdd(Y + row * 10 + r, yacc[rg][q]);
                }
        }
    }
    #undef STG
}

extern "C" void kernel_launch(void* const* d_in, const int* in_sizes, int n_in,
                              void* d_out, int out_size, void* d_ws, size_t ws_size,
                              hipStream_t stream) {
    const float* x   = (const float*)d_in[0];
    const float* mu1 = (const float*)d_in[1];
    const float* p1  = (const float*)d_in[2];
    const float* e1  = (const float*)d_in[3];
    const float* mu2 = (const float*)d_in[4];
    const float* p2  = (const float*)d_in[5];
    const float* e2  = (const float*)d_in[6];
    const float* mu3 = (const float*)d_in[7];
    const float* p3  = (const float*)d_in[8];
    const float* e3  = (const float*)d_in[9];
    float* out = (float*)d_out;

    const int B = 65536, D = 512, DO = 10;

    char* ws = (char*)d_ws;
    u8* Wt1 = (u8*)(ws);                       // 256 KB
    u8* Wt2 = (u8*)(ws + 262144);              // 256 KB
    u8* Wt3 = (u8*)(ws + 524288);              // 8 KB
    u8* xb  = (u8*)(ws + 1048576);             // 32 MB
    u8* h1  = (u8*)(ws + 1048576 + 33554432);  // 32 MB

    float* osc = out + (long)B * DO;

    hipMemsetAsync(out, 0, (size_t)out_size * sizeof(float), stream);
    hipLaunchKernelGGL(k_prep_all, dim3(528), dim3(256), 0, stream,
                       mu1, p1, e1, mu2, p2, e2, mu3, p3, e3, Wt1, Wt2, Wt3, osc);
    hipLaunchKernelGGL(k_cvt8, dim3(2048), dim3(256), 0, stream,
                       (const float4*)x, (uint2*)xb, B * D / 8);
    hipLaunchKernelGGL((k_g8<false>), dim3(512), dim3(512), 0, stream,
                       xb, Wt1, h1, (const u8*)nullptr, (float*)nullptr);
    hipLaunchKernelGGL((k_g8<true>), dim3(512), dim3(512), 0, stream,
                       h1, Wt2, (u8*)nullptr, Wt3, out);
}